// Round 9
// baseline (50.531 us; speedup 1.0000x reference)
//
#include <hip/hip_runtime.h>

#define EPSV   1e-6f
#define SMOOTH 0.025f
#define HALF   4096      // chunk0 = [0,4096), chunk1 = [4096,T)
#define WARM   512       // EMA warm-up steps for chunk1 (a^512 ~ 2.4e-6)

typedef float v4f __attribute__((ext_vector_type(4)));

__device__ __forceinline__ float fast_log2(float v) { return __builtin_amdgcn_logf(v); }
__device__ __forceinline__ float fast_exp2(float v) { return __builtin_amdgcn_exp2f(v); }

struct KC {
    float a1, a2, a3, a4;                  // a^k
    float e0m, e1m, e2m, e3m, e4m, e5m;    // a^(4*2^s), PRE-MASKED by (lane>=d)
    float a4lane;                          // a^(4*lane)
    float a256;                            // a^256
    int   lane;
};

// One KS level for both interleaved chains. Coefficients are pre-masked
// (0 for lanes below the shift distance), so no per-step cndmask:
// fmaf(0, garbage, P) == P for finite inputs.
#define KS2(PA, PB, d, em) \
    uA = __shfl_up(PA, d, 64); uB = __shfl_up(PB, d, 64); \
    PA = fmaf(em, uA, PA);     PB = fmaf(em, uB, PB);

// Scan of M_t = a*M_{t-1} + b*x_t over a 512-elem group laid out as two
// coalesced 256-elem tiles (lane owns A[4l..4l+3], B[256+4l..]).
__device__ __forceinline__ void scan_group(const KC& c,
                                           const float xa[4], const float xb[4],
                                           float& m0, float Ma[4], float Mb[4]) {
    const float b = SMOOTH;
    float qa0 = b * xa[0];
    float qa1 = fmaf(c.a1, qa0, b * xa[1]);
    float qa2 = fmaf(c.a1, qa1, b * xa[2]);
    float qa3 = fmaf(c.a1, qa2, b * xa[3]);
    float qb0 = b * xb[0];
    float qb1 = fmaf(c.a1, qb0, b * xb[1]);
    float qb2 = fmaf(c.a1, qb1, b * xb[2]);
    float qb3 = fmaf(c.a1, qb2, b * xb[3]);

    float PA = qa3, PB = qb3, uA, uB;
    KS2(PA, PB, 1,  c.e0m)
    KS2(PA, PB, 2,  c.e1m)
    KS2(PA, PB, 4,  c.e2m)
    KS2(PA, PB, 8,  c.e3m)
    KS2(PA, PB, 16, c.e4m)
    KS2(PA, PB, 32, c.e5m)

    float TA = __shfl(PA, 63, 64);              // tile totals
    float TB = __shfl(PB, 63, 64);
    float EA = __shfl_up(PA, 1, 64); if (c.lane == 0) EA = 0.f;
    float EB = __shfl_up(PB, 1, 64); if (c.lane == 0) EB = 0.f;

    float mA = m0;                              // state entering tile A
    float mB = fmaf(c.a256, mA, TA);            // entering tile B
    m0       = fmaf(c.a256, mB, TB);            // carry out

    float sA = fmaf(c.a4lane, mA, EA);
    float sB = fmaf(c.a4lane, mB, EB);
    Ma[0] = fmaf(c.a1, sA, qa0); Ma[1] = fmaf(c.a2, sA, qa1);
    Ma[2] = fmaf(c.a3, sA, qa2); Ma[3] = fmaf(c.a4, sA, qa3);
    Mb[0] = fmaf(c.a1, sB, qb0); Mb[1] = fmaf(c.a2, sB, qb1);
    Mb[2] = fmaf(c.a3, sB, qb2); Mb[3] = fmaf(c.a4, sB, qb3);
}

// norm + delta (common prefix of both r-paths)
__device__ __forceinline__ float pcen_norm(float xr, float M, float nalpha, float delta) {
    float m = EPSV + M;
    return fmaf(xr, fast_exp2(nalpha * fast_log2(m)), delta);
}

__global__ __launch_bounds__(256, 6) void pcen_ema_kernel(
    const float* __restrict__ x,
    const float* __restrict__ alpha_p,
    const float* __restrict__ delta_p,
    const float* __restrict__ r_p,
    float* __restrict__ y,
    int rows, int T)
{
    const int gid   = blockIdx.x * blockDim.x + threadIdx.x;
    const int wave  = gid >> 6;
    const int lane  = gid & 63;
    const int row   = wave >> 1;
    const int chunk = wave & 1;
    if (row >= rows) return;

    const float nalpha = -alpha_p[0];
    const float delta  = delta_p[0];
    const float r      = r_p[0];
    const bool  rhalf  = (r == 0.5f);
    const float dr     = rhalf ? __builtin_sqrtf(delta)
                               : fast_exp2(r * fast_log2(delta));

    KC c;
    c.lane = lane;
    const float a = 1.0f - SMOOTH;
    c.a1 = a;  c.a2 = a * a;  c.a3 = c.a2 * a;  c.a4 = c.a2 * c.a2;
    const float e0 = c.a4;       const float e1 = e0 * e0;
    const float e2 = e1 * e1;    const float e3 = e2 * e2;
    const float e4 = e3 * e3;    const float e5 = e4 * e4;
    c.a256 = e5 * e5;
    c.e0m = lane >= 1  ? e0 : 0.f;
    c.e1m = lane >= 2  ? e1 : 0.f;
    c.e2m = lane >= 4  ? e2 : 0.f;
    c.e3m = lane >= 8  ? e3 : 0.f;
    c.e4m = lane >= 16 ? e4 : 0.f;
    c.e5m = lane >= 32 ? e5 : 0.f;
    float a4l = 1.0f;
    if (lane & 1)  a4l *= e0;
    if (lane & 2)  a4l *= e1;
    if (lane & 4)  a4l *= e2;
    if (lane & 8)  a4l *= e3;
    if (lane & 16) a4l *= e4;
    if (lane & 32) a4l *= e5;
    c.a4lane = a4l;

    const long long base = (long long)row * T;
    const float* __restrict__ xrow = x + base;
    float* __restrict__       yrow = y + base;

    const int tstart = chunk ? HALF : 0;
    const int tend   = chunk ? T    : HALF;   // 4096 / 8000
    const int off    = 4 * lane;
    const int lim    = tend - 4;              // clamp for remainder loads

    float m0 = 0.0f;

    // chunk1: 512-step warm-up (no stores); M outputs dead -> DCE'd
    if (chunk) {
        const int tw = HALF - WARM;
        v4f wa = *(const v4f*)(xrow + tw + off);
        v4f wb = *(const v4f*)(xrow + tw + 256 + off);
        float xa[4] = { fmaxf(wa.x,0.f), fmaxf(wa.y,0.f), fmaxf(wa.z,0.f), fmaxf(wa.w,0.f) };
        float xb[4] = { fmaxf(wb.x,0.f), fmaxf(wb.y,0.f), fmaxf(wb.z,0.f), fmaxf(wb.w,0.f) };
        float Md[4], Me[4];
        scan_group(c, xa, xb, m0, Md, Me);
    }

    // main loop: 512-elem groups, 2-DEEP software prefetch (issue distance
    // ~2 group-times > HBM latency). chunk0: 8 full groups; chunk1: 7 full
    // + 320-elem remainder via clamped loads + predicated stores (clamped
    // scan positions come after all stored ones, so they can't corrupt).
    const int ngrp = ((tend - tstart) + 511) >> 9;   // 8 for both chunks
    int t = tstart;

    v4f va, vb, wa, wb;
    {
        int p0 = t + off,        p1 = t + 256 + off;
        va = *(const v4f*)(xrow + (p0 < lim ? p0 : lim));
        vb = *(const v4f*)(xrow + (p1 < lim ? p1 : lim));
        int p2 = t + 512 + off,  p3 = t + 768 + off;   // ngrp >= 2 always
        wa = *(const v4f*)(xrow + (p2 < lim ? p2 : lim));
        wb = *(const v4f*)(xrow + (p3 < lim ? p3 : lim));
    }

    for (int i = 0; i < ngrp; ++i) {
        const int tn = t + 512;
        // prefetch group i+2 (wave-uniform clamp keeps address in-row)
        const int tp = (i + 2 < ngrp) ? t + 1024 : t;
        int p0 = tp + off, p1 = tp + 256 + off;
        v4f za = *(const v4f*)(xrow + (p0 < lim ? p0 : lim));
        v4f zb = *(const v4f*)(xrow + (p1 < lim ? p1 : lim));

        float xa[4] = { fmaxf(va.x,0.f), fmaxf(va.y,0.f), fmaxf(va.z,0.f), fmaxf(va.w,0.f) };
        float xb[4] = { fmaxf(vb.x,0.f), fmaxf(vb.y,0.f), fmaxf(vb.z,0.f), fmaxf(vb.w,0.f) };
        float Ma[4], Mb[4];
        scan_group(c, xa, xb, m0, Ma, Mb);

        float pa0 = pcen_norm(xa[0], Ma[0], nalpha, delta);
        float pa1 = pcen_norm(xa[1], Ma[1], nalpha, delta);
        float pa2 = pcen_norm(xa[2], Ma[2], nalpha, delta);
        float pa3 = pcen_norm(xa[3], Ma[3], nalpha, delta);
        float pb0 = pcen_norm(xb[0], Mb[0], nalpha, delta);
        float pb1 = pcen_norm(xb[1], Mb[1], nalpha, delta);
        float pb2 = pcen_norm(xb[2], Mb[2], nalpha, delta);
        float pb3 = pcen_norm(xb[3], Mb[3], nalpha, delta);

        v4f oa, ob;
        if (rhalf) {   // r == 0.5: single v_sqrt replaces exp2(log2)
            oa.x = __builtin_sqrtf(pa0) - dr; oa.y = __builtin_sqrtf(pa1) - dr;
            oa.z = __builtin_sqrtf(pa2) - dr; oa.w = __builtin_sqrtf(pa3) - dr;
            ob.x = __builtin_sqrtf(pb0) - dr; ob.y = __builtin_sqrtf(pb1) - dr;
            ob.z = __builtin_sqrtf(pb2) - dr; ob.w = __builtin_sqrtf(pb3) - dr;
        } else {
            oa.x = fast_exp2(r * fast_log2(pa0)) - dr;
            oa.y = fast_exp2(r * fast_log2(pa1)) - dr;
            oa.z = fast_exp2(r * fast_log2(pa2)) - dr;
            oa.w = fast_exp2(r * fast_log2(pa3)) - dr;
            ob.x = fast_exp2(r * fast_log2(pb0)) - dr;
            ob.y = fast_exp2(r * fast_log2(pb1)) - dr;
            ob.z = fast_exp2(r * fast_log2(pb2)) - dr;
            ob.w = fast_exp2(r * fast_log2(pb3)) - dr;
        }

        if (tn <= tend) {   // full group (the common case)
            __builtin_nontemporal_store(oa, (v4f*)(yrow + t + off));
            __builtin_nontemporal_store(ob, (v4f*)(yrow + t + 256 + off));
        } else {            // remainder group: predicated 16B stores
            if (t + off       + 4 <= tend) __builtin_nontemporal_store(oa, (v4f*)(yrow + t + off));
            if (t + 256 + off + 4 <= tend) __builtin_nontemporal_store(ob, (v4f*)(yrow + t + 256 + off));
        }

        va = wa; vb = wb; wa = za; wb = zb; t = tn;
    }
}

extern "C" void kernel_launch(void* const* d_in, const int* in_sizes, int n_in,
                              void* d_out, int out_size, void* d_ws, size_t ws_size,
                              hipStream_t stream) {
    const float* x     = (const float*)d_in[0];
    const float* alpha = (const float*)d_in[1];
    const float* delta = (const float*)d_in[2];
    const float* r     = (const float*)d_in[3];
    float* y = (float*)d_out;

    const int T     = 8000;
    const int total = in_sizes[0];
    const int rows  = total / T;              // 4096

    const int waves   = rows * 2;             // 2 T-chunks per row
    const int threads = waves * 64;
    const int block   = 256;
    const int grid    = (threads + block - 1) / block;
    pcen_ema_kernel<<<grid, block, 0, stream>>>(x, alpha, delta, r, y, rows, T);
}

// Round 10
// 49.436 us; speedup vs baseline: 1.0221x; 1.0221x over previous
//
#include <hip/hip_runtime.h>

#define EPSV   1e-6f
#define SMOOTH 0.025f
#define CSZ    2048      // chunk size; chunks 0-2 full, chunk 3 = 1856
#define WARM   512       // EMA warm-up steps per chunk (a^512 ~ 2.4e-6)

typedef float v4f __attribute__((ext_vector_type(4)));

__device__ __forceinline__ float fast_log2(float v) { return __builtin_amdgcn_logf(v); }
__device__ __forceinline__ float fast_exp2(float v) { return __builtin_amdgcn_exp2f(v); }

struct KC {
    float a1, a2, a3, a4;                  // a^k
    float e0m, e1m, e2m, e3m, e4m, e5m;    // a^(4*2^s), PRE-MASKED by (lane>=d)
    float a4lane;                          // a^(4*lane)
    float a256;                            // a^256
    int   lane;
};

// One KS level for both interleaved chains; coefficients pre-masked so no
// per-step cndmask (fmaf(0, garbage, P) == P for finite inputs).
#define KS2(PA, PB, d, em) \
    uA = __shfl_up(PA, d, 64); uB = __shfl_up(PB, d, 64); \
    PA = fmaf(em, uA, PA);     PB = fmaf(em, uB, PB);

// Scan of M_t = a*M_{t-1} + b*x_t over a 512-elem group laid out as two
// coalesced 256-elem tiles (lane owns A[4l..4l+3], B[256+4l..]).
__device__ __forceinline__ void scan_group(const KC& c,
                                           const float xa[4], const float xb[4],
                                           float& m0, float Ma[4], float Mb[4]) {
    const float b = SMOOTH;
    float qa0 = b * xa[0];
    float qa1 = fmaf(c.a1, qa0, b * xa[1]);
    float qa2 = fmaf(c.a1, qa1, b * xa[2]);
    float qa3 = fmaf(c.a1, qa2, b * xa[3]);
    float qb0 = b * xb[0];
    float qb1 = fmaf(c.a1, qb0, b * xb[1]);
    float qb2 = fmaf(c.a1, qb1, b * xb[2]);
    float qb3 = fmaf(c.a1, qb2, b * xb[3]);

    float PA = qa3, PB = qb3, uA, uB;
    KS2(PA, PB, 1,  c.e0m)
    KS2(PA, PB, 2,  c.e1m)
    KS2(PA, PB, 4,  c.e2m)
    KS2(PA, PB, 8,  c.e3m)
    KS2(PA, PB, 16, c.e4m)
    KS2(PA, PB, 32, c.e5m)

    float TA = __shfl(PA, 63, 64);              // tile totals
    float TB = __shfl(PB, 63, 64);
    float EA = __shfl_up(PA, 1, 64); if (c.lane == 0) EA = 0.f;
    float EB = __shfl_up(PB, 1, 64); if (c.lane == 0) EB = 0.f;

    float mA = m0;                              // state entering tile A
    float mB = fmaf(c.a256, mA, TA);            // entering tile B
    m0       = fmaf(c.a256, mB, TB);            // carry out

    float sA = fmaf(c.a4lane, mA, EA);
    float sB = fmaf(c.a4lane, mB, EB);
    Ma[0] = fmaf(c.a1, sA, qa0); Ma[1] = fmaf(c.a2, sA, qa1);
    Ma[2] = fmaf(c.a3, sA, qa2); Ma[3] = fmaf(c.a4, sA, qa3);
    Mb[0] = fmaf(c.a1, sB, qb0); Mb[1] = fmaf(c.a2, sB, qb1);
    Mb[2] = fmaf(c.a3, sB, qb2); Mb[3] = fmaf(c.a4, sB, qb3);
}

// norm + delta (common prefix of both r-paths)
__device__ __forceinline__ float pcen_norm(float xr, float M, float nalpha, float delta) {
    float m = EPSV + M;
    return fmaf(xr, fast_exp2(nalpha * fast_log2(m)), delta);
}

__global__ __launch_bounds__(256, 8) void pcen_ema_kernel(
    const float* __restrict__ x,
    const float* __restrict__ alpha_p,
    const float* __restrict__ delta_p,
    const float* __restrict__ r_p,
    float* __restrict__ y,
    int rows, int T)
{
    const int gid   = blockIdx.x * blockDim.x + threadIdx.x;
    const int wave  = gid >> 6;
    const int lane  = gid & 63;
    const int row   = wave >> 2;          // 4 chunks per row
    const int chunk = wave & 3;
    if (row >= rows) return;

    const float nalpha = -alpha_p[0];
    const float delta  = delta_p[0];
    const float r      = r_p[0];
    const bool  rhalf  = (r == 0.5f);
    const float dr     = rhalf ? __builtin_sqrtf(delta)
                               : fast_exp2(r * fast_log2(delta));

    KC c;
    c.lane = lane;
    const float a = 1.0f - SMOOTH;
    c.a1 = a;  c.a2 = a * a;  c.a3 = c.a2 * a;  c.a4 = c.a2 * c.a2;
    const float e0 = c.a4;       const float e1 = e0 * e0;
    const float e2 = e1 * e1;    const float e3 = e2 * e2;
    const float e4 = e3 * e3;    const float e5 = e4 * e4;
    c.a256 = e5 * e5;
    c.e0m = lane >= 1  ? e0 : 0.f;
    c.e1m = lane >= 2  ? e1 : 0.f;
    c.e2m = lane >= 4  ? e2 : 0.f;
    c.e3m = lane >= 8  ? e3 : 0.f;
    c.e4m = lane >= 16 ? e4 : 0.f;
    c.e5m = lane >= 32 ? e5 : 0.f;
    float a4l = 1.0f;
    if (lane & 1)  a4l *= e0;
    if (lane & 2)  a4l *= e1;
    if (lane & 4)  a4l *= e2;
    if (lane & 8)  a4l *= e3;
    if (lane & 16) a4l *= e4;
    if (lane & 32) a4l *= e5;
    c.a4lane = a4l;

    const long long base = (long long)row * T;
    const float* __restrict__ xrow = x + base;
    float* __restrict__       yrow = y + base;

    const int tstart = chunk * CSZ;                       // 0,2048,4096,6144
    const int tend   = (tstart + CSZ < T) ? tstart + CSZ : T;  // chunk3: 8000
    const int off    = 4 * lane;
    const int lim    = tend - 4;          // clamp for remainder loads

    float m0 = 0.0f;

    // warm-up: 512 steps before tstart (no stores); M outputs dead -> DCE'd
    if (chunk != 0) {
        const int tw = tstart - WARM;
        v4f wa = *(const v4f*)(xrow + tw + off);
        v4f wb = *(const v4f*)(xrow + tw + 256 + off);
        float xa[4] = { fmaxf(wa.x,0.f), fmaxf(wa.y,0.f), fmaxf(wa.z,0.f), fmaxf(wa.w,0.f) };
        float xb[4] = { fmaxf(wb.x,0.f), fmaxf(wb.y,0.f), fmaxf(wb.z,0.f), fmaxf(wb.w,0.f) };
        float Md[4], Me[4];
        scan_group(c, xa, xb, m0, Md, Me);
    }

    // main loop: 512-elem groups, 1-deep prefetch (R4's winning structure).
    // chunks 0-2: exactly 4 full groups (no predication). chunk 3: 3 full +
    // 320-elem remainder via clamped loads + predicated stores (clamped
    // scan positions come after all stored ones, so they can't corrupt).
    const int ngrp = ((tend - tstart) + 511) >> 9;   // 4 for all chunks
    int t = tstart;

    v4f va, vb;
    {
        int p0 = t + off, p1 = t + 256 + off;
        va = *(const v4f*)(xrow + (p0 < lim ? p0 : lim));
        vb = *(const v4f*)(xrow + (p1 < lim ? p1 : lim));
    }
    for (int i = 0; i < ngrp; ++i) {
        const int tn = t + 512;
        // prefetch group i+1 (wave-uniform select keeps address in-row)
        const int tp = (i + 1 < ngrp) ? tn : t;
        int p0 = tp + off, p1 = tp + 256 + off;
        v4f na = *(const v4f*)(xrow + (p0 < lim ? p0 : lim));
        v4f nb = *(const v4f*)(xrow + (p1 < lim ? p1 : lim));

        float xa[4] = { fmaxf(va.x,0.f), fmaxf(va.y,0.f), fmaxf(va.z,0.f), fmaxf(va.w,0.f) };
        float xb[4] = { fmaxf(vb.x,0.f), fmaxf(vb.y,0.f), fmaxf(vb.z,0.f), fmaxf(vb.w,0.f) };
        float Ma[4], Mb[4];
        scan_group(c, xa, xb, m0, Ma, Mb);

        float pa0 = pcen_norm(xa[0], Ma[0], nalpha, delta);
        float pa1 = pcen_norm(xa[1], Ma[1], nalpha, delta);
        float pa2 = pcen_norm(xa[2], Ma[2], nalpha, delta);
        float pa3 = pcen_norm(xa[3], Ma[3], nalpha, delta);
        float pb0 = pcen_norm(xb[0], Mb[0], nalpha, delta);
        float pb1 = pcen_norm(xb[1], Mb[1], nalpha, delta);
        float pb2 = pcen_norm(xb[2], Mb[2], nalpha, delta);
        float pb3 = pcen_norm(xb[3], Mb[3], nalpha, delta);

        v4f oa, ob;
        if (rhalf) {   // r == 0.5: single v_sqrt replaces exp2(log2)
            oa.x = __builtin_sqrtf(pa0) - dr; oa.y = __builtin_sqrtf(pa1) - dr;
            oa.z = __builtin_sqrtf(pa2) - dr; oa.w = __builtin_sqrtf(pa3) - dr;
            ob.x = __builtin_sqrtf(pb0) - dr; ob.y = __builtin_sqrtf(pb1) - dr;
            ob.z = __builtin_sqrtf(pb2) - dr; ob.w = __builtin_sqrtf(pb3) - dr;
        } else {
            oa.x = fast_exp2(r * fast_log2(pa0)) - dr;
            oa.y = fast_exp2(r * fast_log2(pa1)) - dr;
            oa.z = fast_exp2(r * fast_log2(pa2)) - dr;
            oa.w = fast_exp2(r * fast_log2(pa3)) - dr;
            ob.x = fast_exp2(r * fast_log2(pb0)) - dr;
            ob.y = fast_exp2(r * fast_log2(pb1)) - dr;
            ob.z = fast_exp2(r * fast_log2(pb2)) - dr;
            ob.w = fast_exp2(r * fast_log2(pb3)) - dr;
        }

        if (tn <= tend) {   // full group (the common case)
            __builtin_nontemporal_store(oa, (v4f*)(yrow + t + off));
            __builtin_nontemporal_store(ob, (v4f*)(yrow + t + 256 + off));
        } else {            // remainder group: predicated 16B stores
            if (t + off       + 4 <= tend) __builtin_nontemporal_store(oa, (v4f*)(yrow + t + off));
            if (t + 256 + off + 4 <= tend) __builtin_nontemporal_store(ob, (v4f*)(yrow + t + 256 + off));
        }

        va = na; vb = nb; t = tn;
    }
}

extern "C" void kernel_launch(void* const* d_in, const int* in_sizes, int n_in,
                              void* d_out, int out_size, void* d_ws, size_t ws_size,
                              hipStream_t stream) {
    const float* x     = (const float*)d_in[0];
    const float* alpha = (const float*)d_in[1];
    const float* delta = (const float*)d_in[2];
    const float* r     = (const float*)d_in[3];
    float* y = (float*)d_out;

    const int T     = 8000;
    const int total = in_sizes[0];
    const int rows  = total / T;              // 4096

    const int waves   = rows * 4;             // 4 T-chunks per row
    const int threads = waves * 64;
    const int block   = 256;
    const int grid    = (threads + block - 1) / block;
    pcen_ema_kernel<<<grid, block, 0, stream>>>(x, alpha, delta, r, y, rows, T);
}

// Round 11
// 47.866 us; speedup vs baseline: 1.0557x; 1.0328x over previous
//
#include <hip/hip_runtime.h>

#define EPSV   1e-6f
#define SMOOTH 0.025f
#define HALF   4096      // chunk0 = [0,4096), chunk1 = [4096,T)
#define WARM   512       // EMA warm-up steps for chunk1 (a^512 ~ 2.4e-6)

typedef float v4f __attribute__((ext_vector_type(4)));

__device__ __forceinline__ float fast_log2(float v) { return __builtin_amdgcn_logf(v); }
__device__ __forceinline__ float fast_exp2(float v) { return __builtin_amdgcn_exp2f(v); }

struct KC {
    float a1, a2, a3, a4;                  // a^k
    float e0m, e1m, e2m, e3m, e4m, e5m;    // a^(4*2^s), PRE-MASKED by (lane>=d)
    float a4lane;                          // a^(4*lane)
    float a256;                            // a^256
    int   lane;
};

// One KS level for both interleaved chains; coefficients pre-masked so no
// per-step cndmask (fmaf(0, garbage, P) == P for finite inputs).
#define KS2(PA, PB, d, em) \
    uA = __shfl_up(PA, d, 64); uB = __shfl_up(PB, d, 64); \
    PA = fmaf(em, uA, PA);     PB = fmaf(em, uB, PB);

// Scan of M_t = a*M_{t-1} + b*x_t over a 512-elem group laid out as two
// coalesced 256-elem tiles (lane owns A[4l..4l+3], B[256+4l..]). The two
// Kogge-Stone chains are independent and interleave; the inter-group carry
// enters only via 2 trailing FMAs.
__device__ __forceinline__ void scan_group(const KC& c,
                                           const float xa[4], const float xb[4],
                                           float& m0, float Ma[4], float Mb[4]) {
    const float b = SMOOTH;
    float qa0 = b * xa[0];
    float qa1 = fmaf(c.a1, qa0, b * xa[1]);
    float qa2 = fmaf(c.a1, qa1, b * xa[2]);
    float qa3 = fmaf(c.a1, qa2, b * xa[3]);
    float qb0 = b * xb[0];
    float qb1 = fmaf(c.a1, qb0, b * xb[1]);
    float qb2 = fmaf(c.a1, qb1, b * xb[2]);
    float qb3 = fmaf(c.a1, qb2, b * xb[3]);

    float PA = qa3, PB = qb3, uA, uB;
    KS2(PA, PB, 1,  c.e0m)
    KS2(PA, PB, 2,  c.e1m)
    KS2(PA, PB, 4,  c.e2m)
    KS2(PA, PB, 8,  c.e3m)
    KS2(PA, PB, 16, c.e4m)
    KS2(PA, PB, 32, c.e5m)

    float TA = __shfl(PA, 63, 64);              // tile totals
    float TB = __shfl(PB, 63, 64);
    float EA = __shfl_up(PA, 1, 64); if (c.lane == 0) EA = 0.f;
    float EB = __shfl_up(PB, 1, 64); if (c.lane == 0) EB = 0.f;

    float mA = m0;                              // state entering tile A
    float mB = fmaf(c.a256, mA, TA);            // entering tile B
    m0       = fmaf(c.a256, mB, TB);            // carry out

    float sA = fmaf(c.a4lane, mA, EA);
    float sB = fmaf(c.a4lane, mB, EB);
    Ma[0] = fmaf(c.a1, sA, qa0); Ma[1] = fmaf(c.a2, sA, qa1);
    Ma[2] = fmaf(c.a3, sA, qa2); Ma[3] = fmaf(c.a4, sA, qa3);
    Mb[0] = fmaf(c.a1, sB, qb0); Mb[1] = fmaf(c.a2, sB, qb1);
    Mb[2] = fmaf(c.a3, sB, qb2); Mb[3] = fmaf(c.a4, sB, qb3);
}

// norm + delta (common prefix of both r-paths)
__device__ __forceinline__ float pcen_norm(float xr, float M, float nalpha, float delta) {
    float m = EPSV + M;
    return fmaf(xr, fast_exp2(nalpha * fast_log2(m)), delta);
}

__global__ __launch_bounds__(256, 8) void pcen_ema_kernel(
    const float* __restrict__ x,
    const float* __restrict__ alpha_p,
    const float* __restrict__ delta_p,
    const float* __restrict__ r_p,
    float* __restrict__ y,
    int rows, int T)
{
    const int gid   = blockIdx.x * blockDim.x + threadIdx.x;
    const int wave  = gid >> 6;
    const int lane  = gid & 63;
    const int row   = wave >> 1;
    const int chunk = wave & 1;
    if (row >= rows) return;

    const float nalpha = -alpha_p[0];
    const float delta  = delta_p[0];
    const float r      = r_p[0];
    const bool  rhalf  = (r == 0.5f);
    const float dr     = rhalf ? __builtin_sqrtf(delta)
                               : fast_exp2(r * fast_log2(delta));

    KC c;
    c.lane = lane;
    const float a = 1.0f - SMOOTH;
    c.a1 = a;  c.a2 = a * a;  c.a3 = c.a2 * a;  c.a4 = c.a2 * c.a2;
    const float e0 = c.a4;       const float e1 = e0 * e0;
    const float e2 = e1 * e1;    const float e3 = e2 * e2;
    const float e4 = e3 * e3;    const float e5 = e4 * e4;
    c.a256 = e5 * e5;
    c.e0m = lane >= 1  ? e0 : 0.f;
    c.e1m = lane >= 2  ? e1 : 0.f;
    c.e2m = lane >= 4  ? e2 : 0.f;
    c.e3m = lane >= 8  ? e3 : 0.f;
    c.e4m = lane >= 16 ? e4 : 0.f;
    c.e5m = lane >= 32 ? e5 : 0.f;
    float a4l = 1.0f;
    if (lane & 1)  a4l *= e0;
    if (lane & 2)  a4l *= e1;
    if (lane & 4)  a4l *= e2;
    if (lane & 8)  a4l *= e3;
    if (lane & 16) a4l *= e4;
    if (lane & 32) a4l *= e5;
    c.a4lane = a4l;

    const long long base = (long long)row * T;
    const float* __restrict__ xrow = x + base;
    float* __restrict__       yrow = y + base;

    const int tstart = chunk ? HALF : 0;
    const int tend   = chunk ? T    : HALF;   // 4096 / 8000
    const int off    = 4 * lane;
    const int lim    = tend - 4;              // clamp for remainder loads

    float m0 = 0.0f;

    // chunk1: 512-step warm-up (no stores); M outputs dead -> DCE'd
    if (chunk) {
        const int tw = HALF - WARM;
        v4f wa = *(const v4f*)(xrow + tw + off);
        v4f wb = *(const v4f*)(xrow + tw + 256 + off);
        float xa[4] = { fmaxf(wa.x,0.f), fmaxf(wa.y,0.f), fmaxf(wa.z,0.f), fmaxf(wa.w,0.f) };
        float xb[4] = { fmaxf(wb.x,0.f), fmaxf(wb.y,0.f), fmaxf(wb.z,0.f), fmaxf(wb.w,0.f) };
        float Md[4], Me[4];
        scan_group(c, xa, xb, m0, Md, Me);
    }

    // main loop: 512-elem groups, 1-deep prefetch (R4's winning structure).
    // chunk0: 8 full groups; chunk1: 7 full + 320-elem remainder via clamped
    // loads + predicated stores (clamped scan positions come after all
    // stored positions, and the post-remainder carry is dead).
    const int ngrp = ((tend - tstart) + 511) >> 9;   // 8 for both chunks
    int t = tstart;

    v4f va, vb;
    {
        int p0 = t + off, p1 = t + 256 + off;
        va = *(const v4f*)(xrow + (p0 < lim ? p0 : lim));
        vb = *(const v4f*)(xrow + (p1 < lim ? p1 : lim));
    }
    for (int i = 0; i < ngrp; ++i) {
        const int tn = t + 512;
        // prefetch group i+1 (wave-uniform select keeps address in-row)
        const int tp = (i + 1 < ngrp) ? tn : t;
        int p0 = tp + off, p1 = tp + 256 + off;
        v4f na = *(const v4f*)(xrow + (p0 < lim ? p0 : lim));
        v4f nb = *(const v4f*)(xrow + (p1 < lim ? p1 : lim));

        float xa[4] = { fmaxf(va.x,0.f), fmaxf(va.y,0.f), fmaxf(va.z,0.f), fmaxf(va.w,0.f) };
        float xb[4] = { fmaxf(vb.x,0.f), fmaxf(vb.y,0.f), fmaxf(vb.z,0.f), fmaxf(vb.w,0.f) };
        float Ma[4], Mb[4];
        scan_group(c, xa, xb, m0, Ma, Mb);

        float pa0 = pcen_norm(xa[0], Ma[0], nalpha, delta);
        float pa1 = pcen_norm(xa[1], Ma[1], nalpha, delta);
        float pa2 = pcen_norm(xa[2], Ma[2], nalpha, delta);
        float pa3 = pcen_norm(xa[3], Ma[3], nalpha, delta);
        float pb0 = pcen_norm(xb[0], Mb[0], nalpha, delta);
        float pb1 = pcen_norm(xb[1], Mb[1], nalpha, delta);
        float pb2 = pcen_norm(xb[2], Mb[2], nalpha, delta);
        float pb3 = pcen_norm(xb[3], Mb[3], nalpha, delta);

        v4f oa, ob;
        if (rhalf) {   // r == 0.5: single v_sqrt replaces exp2(log2)+mul
            oa.x = __builtin_sqrtf(pa0) - dr; oa.y = __builtin_sqrtf(pa1) - dr;
            oa.z = __builtin_sqrtf(pa2) - dr; oa.w = __builtin_sqrtf(pa3) - dr;
            ob.x = __builtin_sqrtf(pb0) - dr; ob.y = __builtin_sqrtf(pb1) - dr;
            ob.z = __builtin_sqrtf(pb2) - dr; ob.w = __builtin_sqrtf(pb3) - dr;
        } else {
            oa.x = fast_exp2(r * fast_log2(pa0)) - dr;
            oa.y = fast_exp2(r * fast_log2(pa1)) - dr;
            oa.z = fast_exp2(r * fast_log2(pa2)) - dr;
            oa.w = fast_exp2(r * fast_log2(pa3)) - dr;
            ob.x = fast_exp2(r * fast_log2(pb0)) - dr;
            ob.y = fast_exp2(r * fast_log2(pb1)) - dr;
            ob.z = fast_exp2(r * fast_log2(pb2)) - dr;
            ob.w = fast_exp2(r * fast_log2(pb3)) - dr;
        }

        if (tn <= tend) {   // full group (the common case)
            __builtin_nontemporal_store(oa, (v4f*)(yrow + t + off));
            __builtin_nontemporal_store(ob, (v4f*)(yrow + t + 256 + off));
        } else {            // remainder group: predicated 16B stores
            if (t + off       + 4 <= tend) __builtin_nontemporal_store(oa, (v4f*)(yrow + t + off));
            if (t + 256 + off + 4 <= tend) __builtin_nontemporal_store(ob, (v4f*)(yrow + t + 256 + off));
        }

        va = na; vb = nb; t = tn;
    }
}

extern "C" void kernel_launch(void* const* d_in, const int* in_sizes, int n_in,
                              void* d_out, int out_size, void* d_ws, size_t ws_size,
                              hipStream_t stream) {
    const float* x     = (const float*)d_in[0];
    const float* alpha = (const float*)d_in[1];
    const float* delta = (const float*)d_in[2];
    const float* r     = (const float*)d_in[3];
    float* y = (float*)d_out;

    const int T     = 8000;
    const int total = in_sizes[0];
    const int rows  = total / T;              // 4096

    const int waves   = rows * 2;             // 2 T-chunks per row
    const int threads = waves * 64;
    const int block   = 256;
    const int grid    = (threads + block - 1) / block;
    pcen_ema_kernel<<<grid, block, 0, stream>>>(x, alpha, delta, r, y, rows, T);
}

// Round 12
// 47.836 us; speedup vs baseline: 1.0563x; 1.0006x over previous
//
#include <hip/hip_runtime.h>

#define EPSV   1e-6f
#define SMOOTH 0.025f
#define HALF   4096      // chunk0 = [0,4096), chunk1 = [4096,T)
#define WARM   512       // EMA warm-up steps for chunk1 (a^512 ~ 2.4e-6)

typedef float v4f __attribute__((ext_vector_type(4)));

__device__ __forceinline__ float fast_log2(float v) { return __builtin_amdgcn_logf(v); }
__device__ __forceinline__ float fast_exp2(float v) { return __builtin_amdgcn_exp2f(v); }

// DPP move with compile-time control; unselected/invalid lanes produce 0
// (old=0, bound_ctrl=1). Pure VALU — no DS pipe, ~4-8 cyc latency vs ~30+
// for ds_bpermute-based __shfl.
template<int CTRL, int RMASK>
__device__ __forceinline__ float dpp0(float src) {
    return __int_as_float(__builtin_amdgcn_update_dpp(
        0, __float_as_int(src), CTRL, RMASK, 0xf, true));
}
#define ROW_SHR(n)  (0x110 | (n))
#define ROW_BC15    0x142
#define ROW_BC31    0x143

struct KC {
    float a1, a2, a3, a4;      // a^k
    float e0, e1, e2, e3;      // a^4, a^8, a^16, a^32 (uniform, row_shr levels)
    float c15, c31;            // per-lane cross-row coefficients
    float a4lane;              // a^(4*lane)
    float a256;                // a^256
    float inva4;               // a^-4
};

// Weighted inclusive scan of per-lane block sums via DPP (GCN wave-scan
// idiom): 4 row_shr levels (within 16-lane rows; invalid lanes read 0 so
// uniform coefficients are safe) + row_bcast15 (rows 1,3 += prev even row
// total * a^(4(j+1))) + row_bcast31 (rows 2,3 += rows01 total * coef).
__device__ __forceinline__ float dpp_scan(const KC& c, float P) {
    P = fmaf(c.e0,  dpp0<ROW_SHR(1), 0xf>(P), P);
    P = fmaf(c.e1,  dpp0<ROW_SHR(2), 0xf>(P), P);
    P = fmaf(c.e2,  dpp0<ROW_SHR(4), 0xf>(P), P);
    P = fmaf(c.e3,  dpp0<ROW_SHR(8), 0xf>(P), P);
    P = fmaf(c.c15, dpp0<ROW_BC15, 0xa>(P), P);
    P = fmaf(c.c31, dpp0<ROW_BC31, 0xc>(P), P);
    return P;
}

// Scan of M_t = a*M_{t-1} + b*x_t over a 512-elem group laid out as two
// coalesced 256-elem tiles (lane owns A[4l..4l+3], B[256+4l..]). Two
// interleaved DPP scans; carry via wave-uniform readlane totals; exclusive
// prefix E = (P - q3) * a^-4 (no shfl_up).
__device__ __forceinline__ void scan_group(const KC& c,
                                           const float xa[4], const float xb[4],
                                           float& m0, float Ma[4], float Mb[4]) {
    const float b = SMOOTH;
    float qa0 = b * xa[0];
    float qa1 = fmaf(c.a1, qa0, b * xa[1]);
    float qa2 = fmaf(c.a1, qa1, b * xa[2]);
    float qa3 = fmaf(c.a1, qa2, b * xa[3]);
    float qb0 = b * xb[0];
    float qb1 = fmaf(c.a1, qb0, b * xb[1]);
    float qb2 = fmaf(c.a1, qb1, b * xb[2]);
    float qb3 = fmaf(c.a1, qb2, b * xb[3]);

    float PA = dpp_scan(c, qa3);
    float PB = dpp_scan(c, qb3);

    float TA = __int_as_float(__builtin_amdgcn_readlane(__float_as_int(PA), 63));
    float TB = __int_as_float(__builtin_amdgcn_readlane(__float_as_int(PB), 63));
    float EA = (PA - qa3) * c.inva4;            // exclusive prefix
    float EB = (PB - qb3) * c.inva4;

    float mA = m0;                              // state entering tile A
    float mB = fmaf(c.a256, mA, TA);            // entering tile B
    m0       = fmaf(c.a256, mB, TB);            // carry out

    float sA = fmaf(c.a4lane, mA, EA);
    float sB = fmaf(c.a4lane, mB, EB);
    Ma[0] = fmaf(c.a1, sA, qa0); Ma[1] = fmaf(c.a2, sA, qa1);
    Ma[2] = fmaf(c.a3, sA, qa2); Ma[3] = fmaf(c.a4, sA, qa3);
    Mb[0] = fmaf(c.a1, sB, qb0); Mb[1] = fmaf(c.a2, sB, qb1);
    Mb[2] = fmaf(c.a3, sB, qb2); Mb[3] = fmaf(c.a4, sB, qb3);
}

// norm + delta (common prefix of both r-paths)
__device__ __forceinline__ float pcen_norm(float xr, float M, float nalpha, float delta) {
    float m = EPSV + M;
    return fmaf(xr, fast_exp2(nalpha * fast_log2(m)), delta);
}

__global__ __launch_bounds__(256, 8) void pcen_ema_kernel(
    const float* __restrict__ x,
    const float* __restrict__ alpha_p,
    const float* __restrict__ delta_p,
    const float* __restrict__ r_p,
    float* __restrict__ y,
    int rows, int T)
{
    const int gid   = blockIdx.x * blockDim.x + threadIdx.x;
    const int wave  = gid >> 6;
    const int lane  = gid & 63;
    const int row   = wave >> 1;
    const int chunk = wave & 1;
    if (row >= rows) return;

    const float nalpha = -alpha_p[0];
    const float delta  = delta_p[0];
    const float r      = r_p[0];
    const bool  rhalf  = (r == 0.5f);
    const float dr     = rhalf ? __builtin_sqrtf(delta)
                               : fast_exp2(r * fast_log2(delta));

    KC c;
    const float a = 1.0f - SMOOTH;
    c.a1 = a;  c.a2 = a * a;  c.a3 = c.a2 * a;  c.a4 = c.a2 * c.a2;
    c.e0 = c.a4;              // a^4
    c.e1 = c.e0 * c.e0;       // a^8
    c.e2 = c.e1 * c.e1;       // a^16
    c.e3 = c.e2 * c.e2;       // a^32
    const float e4 = c.e3 * c.e3;   // a^64
    const float e5 = e4 * e4;       // a^128
    c.a256 = e5 * e5;
    c.inva4 = 1.0f / c.a4;

    // per-lane constants
    const int j  = lane & 15;       // position within 16-lane row
    const int rw = lane >> 4;       // row index 0..3
    float a4j = 1.0f;               // a^(4j) via bits of j
    if (j & 1) a4j *= c.e0;
    if (j & 2) a4j *= c.e1;
    if (j & 4) a4j *= c.e2;
    if (j & 8) a4j *= c.e3;
    const float a4j1 = a4j * c.e0;  // a^(4(j+1))
    c.c15 = (rw & 1) ? a4j1 : 0.0f;             // rows 1,3: dist to prev row end
    c.c31 = (rw == 2) ? a4j1
          : (rw == 3) ? a4j1 * e4 : 0.0f;       // rows 2,3: dist to lane31
    // a^(4*lane) = a^(4j) * a^(64*rw)
    float e4p = 1.0f;
    if (rw & 1) e4p *= e4;
    if (rw & 2) e4p *= e5;
    c.a4lane = a4j * e4p;

    const long long base = (long long)row * T;
    const float* __restrict__ xrow = x + base;
    float* __restrict__       yrow = y + base;

    const int tstart = chunk ? HALF : 0;
    const int tend   = chunk ? T    : HALF;   // 4096 / 8000
    const int off    = 4 * lane;
    const int lim    = tend - 4;              // clamp for remainder loads

    float m0 = 0.0f;

    // chunk1: 512-step warm-up (no stores); M outputs dead -> DCE'd
    if (chunk) {
        const int tw = HALF - WARM;
        v4f wa = *(const v4f*)(xrow + tw + off);
        v4f wb = *(const v4f*)(xrow + tw + 256 + off);
        float xa[4] = { fmaxf(wa.x,0.f), fmaxf(wa.y,0.f), fmaxf(wa.z,0.f), fmaxf(wa.w,0.f) };
        float xb[4] = { fmaxf(wb.x,0.f), fmaxf(wb.y,0.f), fmaxf(wb.z,0.f), fmaxf(wb.w,0.f) };
        float Md[4], Me[4];
        scan_group(c, xa, xb, m0, Md, Me);
    }

    // main loop: 512-elem groups, 1-deep prefetch (R4's winning structure).
    // chunk0: 8 full groups; chunk1: 7 full + 320-elem remainder via clamped
    // loads + predicated stores (clamped scan positions come after all
    // stored positions, and the post-remainder carry is dead).
    const int ngrp = ((tend - tstart) + 511) >> 9;   // 8 for both chunks
    int t = tstart;

    v4f va, vb;
    {
        int p0 = t + off, p1 = t + 256 + off;
        va = *(const v4f*)(xrow + (p0 < lim ? p0 : lim));
        vb = *(const v4f*)(xrow + (p1 < lim ? p1 : lim));
    }
    for (int i = 0; i < ngrp; ++i) {
        const int tn = t + 512;
        // prefetch group i+1 (wave-uniform select keeps address in-row)
        const int tp = (i + 1 < ngrp) ? tn : t;
        int p0 = tp + off, p1 = tp + 256 + off;
        v4f na = *(const v4f*)(xrow + (p0 < lim ? p0 : lim));
        v4f nb = *(const v4f*)(xrow + (p1 < lim ? p1 : lim));

        float xa[4] = { fmaxf(va.x,0.f), fmaxf(va.y,0.f), fmaxf(va.z,0.f), fmaxf(va.w,0.f) };
        float xb[4] = { fmaxf(vb.x,0.f), fmaxf(vb.y,0.f), fmaxf(vb.z,0.f), fmaxf(vb.w,0.f) };
        float Ma[4], Mb[4];
        scan_group(c, xa, xb, m0, Ma, Mb);

        float pa0 = pcen_norm(xa[0], Ma[0], nalpha, delta);
        float pa1 = pcen_norm(xa[1], Ma[1], nalpha, delta);
        float pa2 = pcen_norm(xa[2], Ma[2], nalpha, delta);
        float pa3 = pcen_norm(xa[3], Ma[3], nalpha, delta);
        float pb0 = pcen_norm(xb[0], Mb[0], nalpha, delta);
        float pb1 = pcen_norm(xb[1], Mb[1], nalpha, delta);
        float pb2 = pcen_norm(xb[2], Mb[2], nalpha, delta);
        float pb3 = pcen_norm(xb[3], Mb[3], nalpha, delta);

        v4f oa, ob;
        if (rhalf) {   // r == 0.5: single v_sqrt replaces exp2(log2)
            oa.x = __builtin_sqrtf(pa0) - dr; oa.y = __builtin_sqrtf(pa1) - dr;
            oa.z = __builtin_sqrtf(pa2) - dr; oa.w = __builtin_sqrtf(pa3) - dr;
            ob.x = __builtin_sqrtf(pb0) - dr; ob.y = __builtin_sqrtf(pb1) - dr;
            ob.z = __builtin_sqrtf(pb2) - dr; ob.w = __builtin_sqrtf(pb3) - dr;
        } else {
            oa.x = fast_exp2(r * fast_log2(pa0)) - dr;
            oa.y = fast_exp2(r * fast_log2(pa1)) - dr;
            oa.z = fast_exp2(r * fast_log2(pa2)) - dr;
            oa.w = fast_exp2(r * fast_log2(pa3)) - dr;
            ob.x = fast_exp2(r * fast_log2(pb0)) - dr;
            ob.y = fast_exp2(r * fast_log2(pb1)) - dr;
            ob.z = fast_exp2(r * fast_log2(pb2)) - dr;
            ob.w = fast_exp2(r * fast_log2(pb3)) - dr;
        }

        if (tn <= tend) {   // full group (the common case)
            __builtin_nontemporal_store(oa, (v4f*)(yrow + t + off));
            __builtin_nontemporal_store(ob, (v4f*)(yrow + t + 256 + off));
        } else {            // remainder group: predicated 16B stores
            if (t + off       + 4 <= tend) __builtin_nontemporal_store(oa, (v4f*)(yrow + t + off));
            if (t + 256 + off + 4 <= tend) __builtin_nontemporal_store(ob, (v4f*)(yrow + t + 256 + off));
        }

        va = na; vb = nb; t = tn;
    }
}

extern "C" void kernel_launch(void* const* d_in, const int* in_sizes, int n_in,
                              void* d_out, int out_size, void* d_ws, size_t ws_size,
                              hipStream_t stream) {
    const float* x     = (const float*)d_in[0];
    const float* alpha = (const float*)d_in[1];
    const float* delta = (const float*)d_in[2];
    const float* r     = (const float*)d_in[3];
    float* y = (float*)d_out;

    const int T     = 8000;
    const int total = in_sizes[0];
    const int rows  = total / T;              // 4096

    const int waves   = rows * 2;             // 2 T-chunks per row
    const int threads = waves * 64;
    const int block   = 256;
    const int grid    = (threads + block - 1) / block;
    pcen_ema_kernel<<<grid, block, 0, stream>>>(x, alpha, delta, r, y, rows, T);
}